// Round 5
// baseline (743.557 us; speedup 1.0000x reference)
//
#include <hip/hip_runtime.h>
#include <cstdint>
#include <cstddef>

#define DINL __device__ __forceinline__

typedef __attribute__((ext_vector_type(8))) short bf16x8;
typedef __attribute__((ext_vector_type(4))) float f32x4;

// ---- order-preserving float <-> uint encoding for atomic max ----
DINL unsigned f32_ord(float f) {
    unsigned u = __float_as_uint(f);
    return (u & 0x80000000u) ? ~u : (u | 0x80000000u);
}
DINL float ord_f32(unsigned v) {
    return (v & 0x80000000u) ? __uint_as_float(v & 0x7FFFFFFFu)
                             : __uint_as_float(~v);
}

// ---- bf16 split helpers (RNE) ----
DINL unsigned short f2bf(float f) {
    unsigned u = __float_as_uint(f);
    unsigned r = u + 0x7FFFu + ((u >> 16) & 1u);
    return (unsigned short)(r >> 16);
}
DINL float bf2f(unsigned short h) { return __uint_as_float((unsigned)h << 16); }

// ---- async global->LDS, 16B per lane (dest = wave-uniform base + lane*16) ----
#define GLOAD_LDS16(g, l)                                                     \
    __builtin_amdgcn_global_load_lds(                                         \
        (const __attribute__((address_space(1))) void*)(g),                   \
        (__attribute__((address_space(3))) void*)(l), 16, 0, 0)

// =====================================================================
// decompose_a: fp32 [Nrows x 768] -> bf16 hi/lo [Mpad x 768], zero pad
// =====================================================================
__global__ void decompose_a(const float* __restrict__ x,
                            unsigned short* __restrict__ hi,
                            unsigned short* __restrict__ lo,
                            int Nrows, int Mpad) {
    int i4 = blockIdx.x * blockDim.x + threadIdx.x;
    int total = Mpad * 192;
    if (i4 >= total) return;
    int row = i4 / 192;
    float4 v = (row < Nrows) ? ((const float4*)x)[i4]
                             : make_float4(0.f, 0.f, 0.f, 0.f);
    ushort4 h, l;
    h.x = f2bf(v.x); l.x = f2bf(v.x - bf2f(h.x));
    h.y = f2bf(v.y); l.y = f2bf(v.y - bf2f(h.y));
    h.z = f2bf(v.z); l.z = f2bf(v.z - bf2f(h.z));
    h.w = f2bf(v.w); l.w = f2bf(v.w - bf2f(h.w));
    ((ushort4*)hi)[i4] = h;
    ((ushort4*)lo)[i4] = l;
}

// =====================================================================
// decompose_bT: W fp32 [768(K) x 768(N)] -> BhiT/BloT bf16 [768(N) x 768(K)]
// =====================================================================
__global__ __launch_bounds__(256) void decompose_bT(const float* __restrict__ W,
                                                    unsigned short* __restrict__ hiT,
                                                    unsigned short* __restrict__ loT) {
    __shared__ float tile[64][65];
    int k0 = blockIdx.x * 64, n0 = blockIdx.y * 64;
    int t = threadIdx.x;
#pragma unroll
    for (int i = 0; i < 16; ++i) {
        int idx = t + i * 256;
        int r = idx >> 6, c = idx & 63;
        tile[r][c] = W[(size_t)(k0 + r) * 768 + n0 + c];
    }
    __syncthreads();
#pragma unroll
    for (int i = 0; i < 16; ++i) {
        int idx = t + i * 256;
        int r = idx >> 6, c = idx & 63;
        float v = tile[c][r];
        unsigned short h = f2bf(v);
        hiT[(size_t)(n0 + r) * 768 + k0 + c] = h;
        loT[(size_t)(n0 + r) * 768 + k0 + c] = f2bf(v - bf2f(h));
    }
}

// =====================================================================
// Fused split-bf16 MFMA GEMM: C = Ahi*Bhi + Ahi*Blo + Alo*Bhi
// 128x128 tile, BK=32, 4 waves (2x2), 48 MFMA / K-step.
// T3-minimum pipeline: double-buffered LDS (64KB), stage(t+1) issued
// BEFORE compute(t), single vmcnt(0)+raw-barrier per K-step AFTER the
// MFMA cluster (stage latency hides under compute). T5 setprio on MFMAs.
// Epilogue (do_attn): el/er per-head dot via 16-lane xor-reduce.
// =====================================================================
__global__ __launch_bounds__(256) void gemm_fused_bf16(
        const unsigned short* __restrict__ Ahi, const unsigned short* __restrict__ Alo,
        const unsigned short* __restrict__ BThi, const unsigned short* __restrict__ BTlo,
        float* __restrict__ C,
        const float* __restrict__ attl, const float* __restrict__ attr,
        float* __restrict__ el, float* __restrict__ er,
        int Nrows, int do_attn) {
    constexpr int K = 768, NC = 768, BKK = 32, NT = K / BKK;   // 24 K-steps
    __shared__ __align__(16) unsigned short AsH[2][128 * BKK];
    __shared__ __align__(16) unsigned short AsL[2][128 * BKK];
    __shared__ __align__(16) unsigned short BsH[2][128 * BKK];
    __shared__ __align__(16) unsigned short BsL[2][128 * BKK];
    const int t = threadIdx.x, w = t >> 6, l = t & 63;
    const int m0 = blockIdx.x * 128, n0 = blockIdx.y * 128;
    const int wr = w >> 1, wc = w & 1;

    f32x4 acc[4][4] = {};

    const int srow = w * 16 + (l >> 2);
    const int scol = (l & 3) * 8;
    const int kr = (l >> 4) * 8;

    auto stage = [&](int buf, int k0) {
#pragma unroll
        for (int c = 0; c < 2; ++c) {
            const size_t ga = (size_t)(m0 + c * 64 + srow) * K + k0 + scol;
            const size_t gb = (size_t)(n0 + c * 64 + srow) * K + k0 + scol;
            const int lofs = (c * 64 + w * 16) * BKK;
            GLOAD_LDS16(Ahi + ga, &AsH[buf][lofs]);
            GLOAD_LDS16(Alo + ga, &AsL[buf][lofs]);
            GLOAD_LDS16(BThi + gb, &BsH[buf][lofs]);
            GLOAD_LDS16(BTlo + gb, &BsL[buf][lofs]);
        }
    };

    // prologue: fill buffer 0, full drain
    stage(0, 0);
    asm volatile("s_waitcnt vmcnt(0)" ::: "memory");
    __builtin_amdgcn_s_barrier();

    for (int tt = 0; tt < NT; ++tt) {
        const int cur = tt & 1;
        if (tt < NT - 1) stage(cur ^ 1, (tt + 1) * BKK);   // async prefetch

        bf16x8 fbh[4], fbl[4];
#pragma unroll
        for (int j = 0; j < 4; ++j) {
            const int row = (wc * 64 + j * 16 + (l & 15)) * BKK + kr;
            fbh[j] = *(const bf16x8*)&BsH[cur][row];
            fbl[j] = *(const bf16x8*)&BsL[cur][row];
        }
        __builtin_amdgcn_s_setprio(1);
#pragma unroll
        for (int i = 0; i < 4; ++i) {
            const int row = (wr * 64 + i * 16 + (l & 15)) * BKK + kr;
            bf16x8 fah = *(const bf16x8*)&AsH[cur][row];
            bf16x8 fal = *(const bf16x8*)&AsL[cur][row];
#pragma unroll
            for (int j = 0; j < 4; ++j) {
                acc[i][j] = __builtin_amdgcn_mfma_f32_16x16x32_bf16(fah, fbh[j], acc[i][j], 0, 0, 0);
                acc[i][j] = __builtin_amdgcn_mfma_f32_16x16x32_bf16(fah, fbl[j], acc[i][j], 0, 0, 0);
                acc[i][j] = __builtin_amdgcn_mfma_f32_16x16x32_bf16(fal, fbh[j], acc[i][j], 0, 0, 0);
            }
        }
        __builtin_amdgcn_s_setprio(0);

        // prefetch landed + all waves done reading buf[cur]
        asm volatile("s_waitcnt vmcnt(0)" ::: "memory");
        __builtin_amdgcn_s_barrier();
    }

    // C/D layout: col=lane&15, row=(lane>>4)*4+reg  [m89-verified]
    const int crow = m0 + wr * 64 + (l >> 4) * 4;
    const int ccol = n0 + wc * 64 + (l & 15);
#pragma unroll
    for (int i = 0; i < 4; ++i)
#pragma unroll
        for (int j = 0; j < 4; ++j)
#pragma unroll
            for (int r = 0; r < 4; ++r)
                C[(size_t)(crow + i * 16 + r) * NC + ccol + j * 16] = acc[i][j][r];

    if (do_attn) {
        const int h = blockIdx.y * 2 + wc;
        float alc[4], arc[4];
#pragma unroll
        for (int j = 0; j < 4; ++j) {
            alc[j] = attl[h * 64 + (l & 15) + j * 16];
            arc[j] = attr[h * 64 + (l & 15) + j * 16];
        }
#pragma unroll
        for (int i = 0; i < 4; ++i)
#pragma unroll
            for (int r = 0; r < 4; ++r) {
                float sl = 0.f, sr = 0.f;
#pragma unroll
                for (int j = 0; j < 4; ++j) {
                    sl += acc[i][j][r] * alc[j];
                    sr += acc[i][j][r] * arc[j];
                }
#pragma unroll
                for (int o = 1; o < 16; o <<= 1) {
                    sl += __shfl_xor(sl, o);
                    sr += __shfl_xor(sr, o);
                }
                int row = crow + i * 16 + r;
                if ((l & 15) == 0 && row < Nrows) {
                    el[row * 12 + h] = sl;
                    er[row * 12 + h] = sr;
                }
            }
    }
}

// =====================================================================
// el/er standalone (layer 2 only: H=1 head spans all n-blocks)
// =====================================================================
__global__ __launch_bounds__(256) void el_er_kernel(const float* __restrict__ z,
                                                    const float* __restrict__ al,
                                                    const float* __restrict__ ar,
                                                    float* __restrict__ el,
                                                    float* __restrict__ er,
                                                    int N, int H, int Dh) {
    int wid = (blockIdx.x * 256 + threadIdx.x) >> 6;
    int lane = threadIdx.x & 63;
    if (wid >= N * H) return;
    int n = wid / H, h = wid % H;
    const float* zr = z + (size_t)n * (H * Dh) + h * Dh;
    const float* alr = al + h * Dh;
    const float* arr = ar + h * Dh;
    float sl = 0.f, sr = 0.f;
    for (int d = lane; d < Dh; d += 64) {
        float zv = zr[d];
        sl += zv * alr[d];
        sr += zv * arr[d];
    }
#pragma unroll
    for (int o = 32; o; o >>= 1) {
        sl += __shfl_down(sl, o);
        sr += __shfl_down(sr, o);
    }
    if (lane == 0) { el[wid] = sl; er[wid] = sr; }
}

__global__ void init_mdenom(unsigned* __restrict__ m, float* __restrict__ denom, int n) {
    int i = blockIdx.x * blockDim.x + threadIdx.x;
    if (i < n) { m[i] = 0u; denom[i] = 0.f; }
}

__global__ void edge_e_kernel(const int* __restrict__ src, const int* __restrict__ dst,
                              const float* __restrict__ el, const float* __restrict__ er,
                              float* __restrict__ e, unsigned* __restrict__ m,
                              int E, int H) {
    int i = blockIdx.x * blockDim.x + threadIdx.x;
    if (i >= E * H) return;
    int ed = i / H, h = i - ed * H;
    int s = src[ed], d = dst[ed];
    float v = el[s * H + h] + er[d * H + h];
    v = (v >= 0.f) ? v : 0.2f * v;
    e[i] = v;
    atomicMax(&m[d * H + h], f32_ord(v));
}

__global__ void edge_ex_kernel(const int* __restrict__ dst,
                               float* __restrict__ e, const unsigned* __restrict__ m,
                               float* __restrict__ denom, int E, int H) {
    int i = blockIdx.x * blockDim.x + threadIdx.x;
    if (i >= E * H) return;
    int ed = i / H, h = i - ed * H;
    int d = dst[ed];
    float x = expf(e[i] - ord_f32(m[d * H + h]));
    e[i] = x;
    atomicAdd(&denom[d * H + h], x);
}

// =====================================================================
// CSR build
// =====================================================================
__global__ void csr_zero(int* __restrict__ counts, int* __restrict__ cursor, int N) {
    int i = blockIdx.x * blockDim.x + threadIdx.x;
    if (i < N) { counts[i] = 0; cursor[i] = 0; }
}

__global__ void csr_count(const int* __restrict__ dst, int* __restrict__ counts, int E) {
    int i = blockIdx.x * blockDim.x + threadIdx.x;
    if (i < E) atomicAdd(&counts[dst[i]], 1);
}

__global__ __launch_bounds__(1024) void csr_scan(const int* __restrict__ counts,
                                                 int* __restrict__ offsets, int N, int E) {
    __shared__ int part[1024];
    const int t = threadIdx.x;
    const int CH = (N + 1023) / 1024;
    const int base = t * CH;
    int s = 0;
    for (int i = 0; i < CH; ++i) {
        int idx = base + i;
        if (idx < N) s += counts[idx];
    }
    part[t] = s;
    __syncthreads();
    for (int o = 1; o < 1024; o <<= 1) {
        int v = (t >= o) ? part[t - o] : 0;
        __syncthreads();
        part[t] += v;
        __syncthreads();
    }
    int run = (t > 0) ? part[t - 1] : 0;
    for (int i = 0; i < CH; ++i) {
        int idx = base + i;
        if (idx < N) { offsets[idx] = run; run += counts[idx]; }
    }
    if (t == 1023) offsets[N] = E;
}

__global__ void csr_scatter(const int* __restrict__ src, const int* __restrict__ dst,
                            const int* __restrict__ offsets, int* __restrict__ cursor,
                            int* __restrict__ perm, int* __restrict__ psrc, int E) {
    int e = blockIdx.x * blockDim.x + threadIdx.x;
    if (e >= E) return;
    int d = dst[e];
    int pos = offsets[d] + atomicAdd(&cursor[d], 1);
    perm[pos] = e;
    psrc[pos] = src[e];
}

// =====================================================================
// CSR aggregation, fused residual+bias+ELU. One wave per dst node.
// mode==1: write bf16 hi/lo split (next layer's A), grid covers Mpad.
// mode==0: write fp32 out (final layer -> d_out), grid covers N.
// =====================================================================
__global__ __launch_bounds__(256) void aggregate_csr(const int* __restrict__ offsets,
                                                     const int* __restrict__ perm,
                                                     const int* __restrict__ psrc,
                                                     const float* __restrict__ z,
                                                     const float* __restrict__ ex,
                                                     const float* __restrict__ denom,
                                                     const float* __restrict__ bias,
                                                     float* __restrict__ out,
                                                     unsigned short* __restrict__ nAhi,
                                                     unsigned short* __restrict__ nAlo,
                                                     int N, int Mpad, int H, int Dh,
                                                     int use_elu, int mode) {
    int d = (blockIdx.x * 256 + threadIdx.x) >> 6;
    int lane = threadIdx.x & 63;
    int limit = mode ? Mpad : N;
    if (d >= limit) return;

    if (d >= N) {
        ushort4 zz = {0, 0, 0, 0};
#pragma unroll
        for (int q = 0; q < 3; ++q) {
            ((ushort4*)nAhi)[(size_t)d * 192 + lane + 64 * q] = zz;
            ((ushort4*)nAlo)[(size_t)d * 192 + lane + 64 * q] = zz;
        }
        return;
    }

    float inv_den = 0.f;
    if (lane < H) inv_den = 1.0f / denom[d * H + lane];

    const float4* zd = (const float4*)(z + (size_t)d * 768);
    const float4* bv = (const float4*)bias;
    float4 acc[3];
#pragma unroll
    for (int q = 0; q < 3; ++q) {
        float4 a = zd[lane + 64 * q];
        float4 b = bv[lane + 64 * q];
        acc[q] = make_float4(a.x + b.x, a.y + b.y, a.z + b.z, a.w + b.w);
    }

    const int beg = offsets[d], end = offsets[d + 1];
    for (int p = beg; p < end; ++p) {
        int e = perm[p];
        int s = psrc[p];
        float alpha = 0.f;
        if (lane < H) alpha = ex[(size_t)e * H + lane] * inv_den;
        const float4* zs = (const float4*)(z + (size_t)s * 768);
#pragma unroll
        for (int q = 0; q < 3; ++q) {
            int idx = lane + 64 * q;
            int h = (4 * idx) / Dh;
            float a = __shfl(alpha, h);
            float4 zv = zs[idx];
            acc[q].x += a * zv.x;
            acc[q].y += a * zv.y;
            acc[q].z += a * zv.z;
            acc[q].w += a * zv.w;
        }
    }

#pragma unroll
    for (int q = 0; q < 3; ++q) {
        float4 v = acc[q];
        if (use_elu) {
            v.x = v.x > 0.f ? v.x : expm1f(v.x);
            v.y = v.y > 0.f ? v.y : expm1f(v.y);
            v.z = v.z > 0.f ? v.z : expm1f(v.z);
            v.w = v.w > 0.f ? v.w : expm1f(v.w);
        }
        if (mode) {
            ushort4 h4, l4;
            h4.x = f2bf(v.x); l4.x = f2bf(v.x - bf2f(h4.x));
            h4.y = f2bf(v.y); l4.y = f2bf(v.y - bf2f(h4.y));
            h4.z = f2bf(v.z); l4.z = f2bf(v.z - bf2f(h4.z));
            h4.w = f2bf(v.w); l4.w = f2bf(v.w - bf2f(h4.w));
            ((ushort4*)nAhi)[(size_t)d * 192 + lane + 64 * q] = h4;
            ((ushort4*)nAlo)[(size_t)d * 192 + lane + 64 * q] = l4;
        } else {
            ((float4*)(out + (size_t)d * 768))[lane + 64 * q] = v;
        }
    }
}

// =====================================================================
// host-side layer driver
// =====================================================================
static void run_layer(const float* W, const float* al, const float* ar,
                      const float* bias, const int* src, const int* dst,
                      const int* offsets, const int* perm, const int* psrc,
                      unsigned short* Ahi, unsigned short* Alo,
                      unsigned short* BThi, unsigned short* BTlo,
                      float* z, float* out, float* ebuf, float* el, float* er,
                      unsigned* m, float* denom,
                      int N, int Mpad, int E, int H, int Dh, bool use_elu, int mode,
                      hipStream_t stream) {
    decompose_bT<<<dim3(12, 12), 256, 0, stream>>>(W, BThi, BTlo);
    gemm_fused_bf16<<<dim3(Mpad / 128, 6), 256, 0, stream>>>(
        Ahi, Alo, BThi, BTlo, z, al, ar, el, er, N, H == 12 ? 1 : 0);
    if (H != 12)
        el_er_kernel<<<(N * H * 64 + 255) / 256, 256, 0, stream>>>(z, al, ar, el, er, N, H, Dh);
    init_mdenom<<<(N * H + 255) / 256, 256, 0, stream>>>(m, denom, N * H);
    edge_e_kernel<<<(E * H + 255) / 256, 256, 0, stream>>>(src, dst, el, er, ebuf, m, E, H);
    edge_ex_kernel<<<(E * H + 255) / 256, 256, 0, stream>>>(dst, ebuf, m, denom, E, H);
    int waves = mode ? Mpad : N;
    aggregate_csr<<<(waves * 64 + 255) / 256, 256, 0, stream>>>(
        offsets, perm, psrc, z, ebuf, denom, bias, out, Ahi, Alo,
        N, Mpad, H, Dh, use_elu ? 1 : 0, mode);
}

extern "C" void kernel_launch(void* const* d_in, const int* in_sizes, int n_in,
                              void* d_out, int out_size, void* d_ws, size_t ws_size,
                              hipStream_t stream) {
    const float* x0 = (const float*)d_in[0];
    const int* src = (const int*)d_in[1];
    const int* dst = (const int*)d_in[2];
    const float* W[3]  = {(const float*)d_in[3], (const float*)d_in[7],  (const float*)d_in[11]};
    const float* al[3] = {(const float*)d_in[4], (const float*)d_in[8],  (const float*)d_in[12]};
    const float* ar[3] = {(const float*)d_in[5], (const float*)d_in[9],  (const float*)d_in[13]};
    const float* bs[3] = {(const float*)d_in[6], (const float*)d_in[10], (const float*)d_in[14]};

    const int N = in_sizes[0] / 768;           // 20000
    const int E = in_sizes[1];                 // 100000
    const int Mpad = ((N + 127) / 128) * 128;  // 20096

    char* p = (char*)d_ws;
    const size_t FP = (size_t)Mpad * 768 * sizeof(float);
    const size_t BF = (size_t)Mpad * 768 * sizeof(unsigned short);
    float* z = (float*)p;                 p += FP;
    unsigned short* Ahi = (unsigned short*)p;  p += BF;
    unsigned short* Alo = (unsigned short*)p;  p += BF;
    unsigned short* BThi = (unsigned short*)p; p += (size_t)768 * 768 * 2;
    unsigned short* BTlo = (unsigned short*)p; p += (size_t)768 * 768 * 2;
    float* ebuf = (float*)p;              p += (size_t)E * 12 * sizeof(float);
    float* el = (float*)p;                p += (size_t)N * 12 * sizeof(float);
    float* er = (float*)p;                p += (size_t)N * 12 * sizeof(float);
    unsigned* m = (unsigned*)p;           p += (size_t)N * 12 * sizeof(unsigned);
    float* denom = (float*)p;             p += (size_t)N * 12 * sizeof(float);
    int* counts = (int*)p;                p += (size_t)N * sizeof(int);
    int* cursor = (int*)p;                p += (size_t)N * sizeof(int);
    int* offsets = (int*)p;               p += (size_t)(N + 4) * sizeof(int);
    int* perm = (int*)p;                  p += (size_t)E * sizeof(int);
    int* psrc = (int*)p;                  p += (size_t)E * sizeof(int);

    // ---- CSR (dst-sorted edges), static across layers ----
    csr_zero<<<(N + 255) / 256, 256, 0, stream>>>(counts, cursor, N);
    csr_count<<<(E + 255) / 256, 256, 0, stream>>>(dst, counts, E);
    csr_scan<<<1, 1024, 0, stream>>>(counts, offsets, N, E);
    csr_scatter<<<(E + 255) / 256, 256, 0, stream>>>(src, dst, offsets, cursor, perm, psrc, E);

    // layer 0 input split
    decompose_a<<<(Mpad * 192 + 255) / 256, 256, 0, stream>>>(x0, Ahi, Alo, N, Mpad);

    // L0, L1: aggregate writes next layer's split into Ahi/Alo (mode 1)
    run_layer(W[0], al[0], ar[0], bs[0], src, dst, offsets, perm, psrc,
              Ahi, Alo, BThi, BTlo, z, nullptr, ebuf, el, er, m, denom,
              N, Mpad, E, 12, 64, true, 1, stream);
    run_layer(W[1], al[1], ar[1], bs[1], src, dst, offsets, perm, psrc,
              Ahi, Alo, BThi, BTlo, z, nullptr, ebuf, el, er, m, denom,
              N, Mpad, E, 12, 64, true, 1, stream);
    // L2: fp32 out -> d_out (mode 0)
    run_layer(W[2], al[2], ar[2], bs[2], src, dst, offsets, perm, psrc,
              Ahi, Alo, BThi, BTlo, z, (float*)d_out, ebuf, el, er, m, denom,
              N, Mpad, E, 1, 768, false, 0, stream);
}

// Round 9
// 708.481 us; speedup vs baseline: 1.0495x; 1.0495x over previous
//
#include <hip/hip_runtime.h>
#include <cstdint>
#include <cstddef>

#define DINL __device__ __forceinline__

typedef __attribute__((ext_vector_type(8))) short bf16x8;
typedef __attribute__((ext_vector_type(4))) float f32x4;

// ---- order-preserving float <-> uint encoding for atomic max ----
DINL unsigned f32_ord(float f) {
    unsigned u = __float_as_uint(f);
    return (u & 0x80000000u) ? ~u : (u | 0x80000000u);
}
DINL float ord_f32(unsigned v) {
    return (v & 0x80000000u) ? __uint_as_float(v & 0x7FFFFFFFu)
                             : __uint_as_float(~v);
}

// ---- bf16 split helpers (RNE) ----
DINL unsigned short f2bf(float f) {
    unsigned u = __float_as_uint(f);
    unsigned r = u + 0x7FFFu + ((u >> 16) & 1u);
    return (unsigned short)(r >> 16);
}
DINL float bf2f(unsigned short h) { return __uint_as_float((unsigned)h << 16); }

// ---- async global->LDS, 16B per lane (dest = wave-uniform base + lane*16) ----
#define GLOAD_LDS16(g, l)                                                     \
    __builtin_amdgcn_global_load_lds(                                         \
        (const __attribute__((address_space(1))) void*)(g),                   \
        (__attribute__((address_space(3))) void*)(l), 16, 0, 0)

// =====================================================================
// decompose_a: fp32 [Nrows x 768] -> bf16 hi/lo [Mpad x 768], zero pad
// =====================================================================
__global__ void decompose_a(const float* __restrict__ x,
                            unsigned short* __restrict__ hi,
                            unsigned short* __restrict__ lo,
                            int Nrows, int Mpad) {
    int i4 = blockIdx.x * blockDim.x + threadIdx.x;
    int total = Mpad * 192;
    if (i4 >= total) return;
    int row = i4 / 192;
    float4 v = (row < Nrows) ? ((const float4*)x)[i4]
                             : make_float4(0.f, 0.f, 0.f, 0.f);
    ushort4 h, l;
    h.x = f2bf(v.x); l.x = f2bf(v.x - bf2f(h.x));
    h.y = f2bf(v.y); l.y = f2bf(v.y - bf2f(h.y));
    h.z = f2bf(v.z); l.z = f2bf(v.z - bf2f(h.z));
    h.w = f2bf(v.w); l.w = f2bf(v.w - bf2f(h.w));
    ((ushort4*)hi)[i4] = h;
    ((ushort4*)lo)[i4] = l;
}

// =====================================================================
// decompose_bT: W fp32 [768(K) x 768(N)] -> BhiT/BloT bf16 [768(N) x 768(K)]
// =====================================================================
__global__ __launch_bounds__(256) void decompose_bT(const float* __restrict__ W,
                                                    unsigned short* __restrict__ hiT,
                                                    unsigned short* __restrict__ loT) {
    __shared__ float tile[64][65];
    int k0 = blockIdx.x * 64, n0 = blockIdx.y * 64;
    int t = threadIdx.x;
#pragma unroll
    for (int i = 0; i < 16; ++i) {
        int idx = t + i * 256;
        int r = idx >> 6, c = idx & 63;
        tile[r][c] = W[(size_t)(k0 + r) * 768 + n0 + c];
    }
    __syncthreads();
#pragma unroll
    for (int i = 0; i < 16; ++i) {
        int idx = t + i * 256;
        int r = idx >> 6, c = idx & 63;
        float v = tile[c][r];
        unsigned short h = f2bf(v);
        hiT[(size_t)(n0 + r) * 768 + k0 + c] = h;
        loT[(size_t)(n0 + r) * 768 + k0 + c] = f2bf(v - bf2f(h));
    }
}

// =====================================================================
// Fused split-bf16 MFMA GEMM: C = Ahi*Bhi + Ahi*Blo + Alo*Bhi
// 128x128 tile, BK=32, 8 waves (4x2, 512 threads), 24 MFMA/wave/K-step.
// 2-phase double-buffered pipeline (64KB LDS -> 2 blocks/CU = 16 waves/CU).
// Epilogue (do_attn): el/er per-head dot via 16-lane xor-reduce.
// =====================================================================
__global__ __launch_bounds__(512) void gemm_fused_bf16(
        const unsigned short* __restrict__ Ahi, const unsigned short* __restrict__ Alo,
        const unsigned short* __restrict__ BThi, const unsigned short* __restrict__ BTlo,
        float* __restrict__ C,
        const float* __restrict__ attl, const float* __restrict__ attr,
        float* __restrict__ el, float* __restrict__ er,
        int Nrows, int do_attn) {
    constexpr int K = 768, NC = 768, BKK = 32, NT = K / BKK;   // 24 K-steps
    __shared__ __align__(16) unsigned short AsH[2][128 * BKK];
    __shared__ __align__(16) unsigned short AsL[2][128 * BKK];
    __shared__ __align__(16) unsigned short BsH[2][128 * BKK];
    __shared__ __align__(16) unsigned short BsL[2][128 * BKK];
    const int t = threadIdx.x, w = t >> 6, l = t & 63;
    const int m0 = blockIdx.x * 128, n0 = blockIdx.y * 128;
    const int wr = w >> 1, wc = w & 1;          // 4x2 wave grid; wave owns 32x64

    f32x4 acc[2][4] = {};

    const int srow = w * 16 + (l >> 2);          // each wave stages 16 rows of all 4 mats
    const int scol = (l & 3) * 8;
    const int kr = (l >> 4) * 8;

    auto stage = [&](int buf, int k0) {
        const size_t ga = (size_t)(m0 + srow) * K + k0 + scol;
        const size_t gb = (size_t)(n0 + srow) * K + k0 + scol;
        const int lofs = (w * 16) * BKK;
        GLOAD_LDS16(Ahi + ga, &AsH[buf][lofs]);
        GLOAD_LDS16(Alo + ga, &AsL[buf][lofs]);
        GLOAD_LDS16(BThi + gb, &BsH[buf][lofs]);
        GLOAD_LDS16(BTlo + gb, &BsL[buf][lofs]);
    };

    // prologue: fill buffer 0, full drain
    stage(0, 0);
    asm volatile("s_waitcnt vmcnt(0)" ::: "memory");
    __builtin_amdgcn_s_barrier();

    for (int tt = 0; tt < NT; ++tt) {
        const int cur = tt & 1;
        if (tt < NT - 1) stage(cur ^ 1, (tt + 1) * BKK);   // async prefetch

        bf16x8 fbh[4], fbl[4];
#pragma unroll
        for (int j = 0; j < 4; ++j) {
            const int row = (wc * 64 + j * 16 + (l & 15)) * BKK + kr;
            fbh[j] = *(const bf16x8*)&BsH[cur][row];
            fbl[j] = *(const bf16x8*)&BsL[cur][row];
        }
        __builtin_amdgcn_s_setprio(1);
#pragma unroll
        for (int i = 0; i < 2; ++i) {
            const int row = (wr * 32 + i * 16 + (l & 15)) * BKK + kr;
            bf16x8 fah = *(const bf16x8*)&AsH[cur][row];
            bf16x8 fal = *(const bf16x8*)&AsL[cur][row];
#pragma unroll
            for (int j = 0; j < 4; ++j) {
                acc[i][j] = __builtin_amdgcn_mfma_f32_16x16x32_bf16(fah, fbh[j], acc[i][j], 0, 0, 0);
                acc[i][j] = __builtin_amdgcn_mfma_f32_16x16x32_bf16(fah, fbl[j], acc[i][j], 0, 0, 0);
                acc[i][j] = __builtin_amdgcn_mfma_f32_16x16x32_bf16(fal, fbh[j], acc[i][j], 0, 0, 0);
            }
        }
        __builtin_amdgcn_s_setprio(0);

        // prefetch landed + all waves done reading buf[cur]
        asm volatile("s_waitcnt vmcnt(0)" ::: "memory");
        __builtin_amdgcn_s_barrier();
    }

    // C/D layout: col=lane&15, row=(lane>>4)*4+reg  [m89-verified]
    const int crow = m0 + wr * 32 + (l >> 4) * 4;
    const int ccol = n0 + wc * 64 + (l & 15);
#pragma unroll
    for (int i = 0; i < 2; ++i)
#pragma unroll
        for (int j = 0; j < 4; ++j)
#pragma unroll
            for (int r = 0; r < 4; ++r)
                C[(size_t)(crow + i * 16 + r) * NC + ccol + j * 16] = acc[i][j][r];

    if (do_attn) {
        const int h = blockIdx.y * 2 + wc;
        float alc[4], arc[4];
#pragma unroll
        for (int j = 0; j < 4; ++j) {
            alc[j] = attl[h * 64 + (l & 15) + j * 16];
            arc[j] = attr[h * 64 + (l & 15) + j * 16];
        }
#pragma unroll
        for (int i = 0; i < 2; ++i)
#pragma unroll
            for (int r = 0; r < 4; ++r) {
                float sl = 0.f, sr = 0.f;
#pragma unroll
                for (int j = 0; j < 4; ++j) {
                    sl += acc[i][j][r] * alc[j];
                    sr += acc[i][j][r] * arc[j];
                }
#pragma unroll
                for (int o = 1; o < 16; o <<= 1) {
                    sl += __shfl_xor(sl, o);
                    sr += __shfl_xor(sr, o);
                }
                int row = crow + i * 16 + r;
                if ((l & 15) == 0 && row < Nrows) {
                    el[row * 12 + h] = sl;
                    er[row * 12 + h] = sr;
                }
            }
    }
}

// =====================================================================
// el/er standalone (layer 2 only: H=1 head spans all n-blocks)
// =====================================================================
__global__ __launch_bounds__(256) void el_er_kernel(const float* __restrict__ z,
                                                    const float* __restrict__ al,
                                                    const float* __restrict__ ar,
                                                    float* __restrict__ el,
                                                    float* __restrict__ er,
                                                    int N, int H, int Dh) {
    int wid = (blockIdx.x * 256 + threadIdx.x) >> 6;
    int lane = threadIdx.x & 63;
    if (wid >= N * H) return;
    int n = wid / H, h = wid % H;
    const float* zr = z + (size_t)n * (H * Dh) + h * Dh;
    const float* alr = al + h * Dh;
    const float* arr = ar + h * Dh;
    float sl = 0.f, sr = 0.f;
    for (int d = lane; d < Dh; d += 64) {
        float zv = zr[d];
        sl += zv * alr[d];
        sr += zv * arr[d];
    }
#pragma unroll
    for (int o = 32; o; o >>= 1) {
        sl += __shfl_down(sl, o);
        sr += __shfl_down(sr, o);
    }
    if (lane == 0) { el[wid] = sl; er[wid] = sr; }
}

__global__ void init_mdenom(unsigned* __restrict__ m, float* __restrict__ denom, int n) {
    int i = blockIdx.x * blockDim.x + threadIdx.x;
    if (i < n) { m[i] = 0u; denom[i] = 0.f; }
}

// =====================================================================
// edge kernels operate in CSR position order (psrc/pdst arrays)
// =====================================================================
__global__ void edge_e_kernel(const int* __restrict__ psrc, const int* __restrict__ pdst,
                              const float* __restrict__ el, const float* __restrict__ er,
                              float* __restrict__ e, unsigned* __restrict__ m,
                              int E, int H) {
    int i = blockIdx.x * blockDim.x + threadIdx.x;
    if (i >= E * H) return;
    int p = i / H, h = i - p * H;
    int s = psrc[p], d = pdst[p];
    float v = el[s * H + h] + er[d * H + h];
    v = (v >= 0.f) ? v : 0.2f * v;
    e[i] = v;
    atomicMax(&m[d * H + h], f32_ord(v));
}

__global__ void edge_ex_kernel(const int* __restrict__ pdst,
                               float* __restrict__ e, const unsigned* __restrict__ m,
                               float* __restrict__ denom, int E, int H) {
    int i = blockIdx.x * blockDim.x + threadIdx.x;
    if (i >= E * H) return;
    int p = i / H, h = i - p * H;
    int d = pdst[p];
    float x = expf(e[i] - ord_f32(m[d * H + h]));
    e[i] = x;
    atomicAdd(&denom[d * H + h], x);
}

// =====================================================================
// CSR build
// =====================================================================
__global__ void csr_zero(int* __restrict__ counts, int* __restrict__ cursor, int N) {
    int i = blockIdx.x * blockDim.x + threadIdx.x;
    if (i < N) { counts[i] = 0; cursor[i] = 0; }
}

__global__ void csr_count(const int* __restrict__ dst, int* __restrict__ counts, int E) {
    int i = blockIdx.x * blockDim.x + threadIdx.x;
    if (i < E) atomicAdd(&counts[dst[i]], 1);
}

__global__ __launch_bounds__(1024) void csr_scan(const int* __restrict__ counts,
                                                 int* __restrict__ offsets, int N, int E) {
    __shared__ int part[1024];
    const int t = threadIdx.x;
    const int CH = (N + 1023) / 1024;
    const int base = t * CH;
    int s = 0;
    for (int i = 0; i < CH; ++i) {
        int idx = base + i;
        if (idx < N) s += counts[idx];
    }
    part[t] = s;
    __syncthreads();
    for (int o = 1; o < 1024; o <<= 1) {
        int v = (t >= o) ? part[t - o] : 0;
        __syncthreads();
        part[t] += v;
        __syncthreads();
    }
    int run = (t > 0) ? part[t - 1] : 0;
    for (int i = 0; i < CH; ++i) {
        int idx = base + i;
        if (idx < N) { offsets[idx] = run; run += counts[idx]; }
    }
    if (t == 1023) offsets[N] = E;
}

__global__ void csr_scatter(const int* __restrict__ src, const int* __restrict__ dst,
                            const int* __restrict__ offsets, int* __restrict__ cursor,
                            int* __restrict__ psrc, int* __restrict__ pdst, int E) {
    int e = blockIdx.x * blockDim.x + threadIdx.x;
    if (e >= E) return;
    int d = dst[e];
    int pos = offsets[d] + atomicAdd(&cursor[d], 1);
    psrc[pos] = src[e];
    pdst[pos] = d;
}

// =====================================================================
// CSR aggregation, fused residual+bias+ELU.
// THREE waves per dst node (one per 256-col segment q), 2-way unrolled
// edge loop. mode==1: write bf16 hi/lo split (next layer's A), covers Mpad.
// mode==0: write fp32 out (final layer -> d_out), covers N.
// =====================================================================
__global__ __launch_bounds__(256) void aggregate_csr(const int* __restrict__ offsets,
                                                     const int* __restrict__ psrc,
                                                     const float* __restrict__ z,
                                                     const float* __restrict__ ex,
                                                     const float* __restrict__ denom,
                                                     const float* __restrict__ bias,
                                                     float* __restrict__ out,
                                                     unsigned short* __restrict__ nAhi,
                                                     unsigned short* __restrict__ nAlo,
                                                     int N, int Mpad, int H, int Dh,
                                                     int use_elu, int mode) {
    int wid = (blockIdx.x * 256 + threadIdx.x) >> 6;
    int lane = threadIdx.x & 63;
    int limit = mode ? Mpad : N;
    int d = wid / 3, q = wid - d * 3;
    if (d >= limit) return;
    const int idx = lane + 64 * q;                 // float4 index in the 768-row

    if (d >= N) {                                  // pad rows: zero split only
        ushort4 zz = {0, 0, 0, 0};
        ((ushort4*)nAhi)[(size_t)d * 192 + idx] = zz;
        ((ushort4*)nAlo)[(size_t)d * 192 + idx] = zz;
        return;
    }

    float inv_den = 0.f;
    if (lane < H) inv_den = 1.0f / denom[d * H + lane];
    const int h = (4 * idx) / Dh;                  // head of this float4

    float4 a = ((const float4*)(z + (size_t)d * 768))[idx];
    float4 b = ((const float4*)bias)[idx];
    float4 acc = make_float4(a.x + b.x, a.y + b.y, a.z + b.z, a.w + b.w);

    const int beg = offsets[d], end = offsets[d + 1];
    int p = beg;
    for (; p + 1 < end; p += 2) {
        int s0 = psrc[p], s1 = psrc[p + 1];
        float al0 = 0.f, al1 = 0.f;
        if (lane < H) {
            al0 = ex[(size_t)p * H + lane] * inv_den;
            al1 = ex[(size_t)(p + 1) * H + lane] * inv_den;
        }
        float4 z0 = ((const float4*)(z + (size_t)s0 * 768))[idx];
        float4 z1 = ((const float4*)(z + (size_t)s1 * 768))[idx];
        float aa0 = __shfl(al0, h), aa1 = __shfl(al1, h);
        acc.x += aa0 * z0.x + aa1 * z1.x;
        acc.y += aa0 * z0.y + aa1 * z1.y;
        acc.z += aa0 * z0.z + aa1 * z1.z;
        acc.w += aa0 * z0.w + aa1 * z1.w;
    }
    if (p < end) {
        int s0 = psrc[p];
        float al0 = 0.f;
        if (lane < H) al0 = ex[(size_t)p * H + lane] * inv_den;
        float4 z0 = ((const float4*)(z + (size_t)s0 * 768))[idx];
        float aa0 = __shfl(al0, h);
        acc.x += aa0 * z0.x;
        acc.y += aa0 * z0.y;
        acc.z += aa0 * z0.z;
        acc.w += aa0 * z0.w;
    }

    float4 v = acc;
    if (use_elu) {
        v.x = v.x > 0.f ? v.x : expm1f(v.x);
        v.y = v.y > 0.f ? v.y : expm1f(v.y);
        v.z = v.z > 0.f ? v.z : expm1f(v.z);
        v.w = v.w > 0.f ? v.w : expm1f(v.w);
    }
    if (mode) {
        ushort4 h4, l4;
        h4.x = f2bf(v.x); l4.x = f2bf(v.x - bf2f(h4.x));
        h4.y = f2bf(v.y); l4.y = f2bf(v.y - bf2f(h4.y));
        h4.z = f2bf(v.z); l4.z = f2bf(v.z - bf2f(h4.z));
        h4.w = f2bf(v.w); l4.w = f2bf(v.w - bf2f(h4.w));
        ((ushort4*)nAhi)[(size_t)d * 192 + idx] = h4;
        ((ushort4*)nAlo)[(size_t)d * 192 + idx] = l4;
    } else {
        ((float4*)(out + (size_t)d * 768))[idx] = v;
    }
}

// =====================================================================
// host-side layer driver
// =====================================================================
static void run_layer(const float* W, const float* al, const float* ar,
                      const float* bias,
                      const int* offsets, const int* psrc, const int* pdst,
                      unsigned short* Ahi, unsigned short* Alo,
                      unsigned short* BThi, unsigned short* BTlo,
                      float* z, float* out, float* ebuf, float* el, float* er,
                      unsigned* m, float* denom,
                      int N, int Mpad, int E, int H, int Dh, bool use_elu, int mode,
                      hipStream_t stream) {
    decompose_bT<<<dim3(12, 12), 256, 0, stream>>>(W, BThi, BTlo);
    gemm_fused_bf16<<<dim3(Mpad / 128, 6), 512, 0, stream>>>(
        Ahi, Alo, BThi, BTlo, z, al, ar, el, er, N, H == 12 ? 1 : 0);
    if (H != 12)
        el_er_kernel<<<(N * H * 64 + 255) / 256, 256, 0, stream>>>(z, al, ar, el, er, N, H, Dh);
    init_mdenom<<<(N * H + 255) / 256, 256, 0, stream>>>(m, denom, N * H);
    edge_e_kernel<<<(E * H + 255) / 256, 256, 0, stream>>>(psrc, pdst, el, er, ebuf, m, E, H);
    edge_ex_kernel<<<(E * H + 255) / 256, 256, 0, stream>>>(pdst, ebuf, m, denom, E, H);
    int limit = mode ? Mpad : N;
    aggregate_csr<<<((size_t)limit * 3 * 64 + 255) / 256, 256, 0, stream>>>(
        offsets, psrc, z, ebuf, denom, bias, out, Ahi, Alo,
        N, Mpad, H, Dh, use_elu ? 1 : 0, mode);
}

extern "C" void kernel_launch(void* const* d_in, const int* in_sizes, int n_in,
                              void* d_out, int out_size, void* d_ws, size_t ws_size,
                              hipStream_t stream) {
    const float* x0 = (const float*)d_in[0];
    const int* src = (const int*)d_in[1];
    const int* dst = (const int*)d_in[2];
    const float* W[3]  = {(const float*)d_in[3], (const float*)d_in[7],  (const float*)d_in[11]};
    const float* al[3] = {(const float*)d_in[4], (const float*)d_in[8],  (const float*)d_in[12]};
    const float* ar[3] = {(const float*)d_in[5], (const float*)d_in[9],  (const float*)d_in[13]};
    const float* bs[3] = {(const float*)d_in[6], (const float*)d_in[10], (const float*)d_in[14]};

    const int N = in_sizes[0] / 768;           // 20000
    const int E = in_sizes[1];                 // 100000
    const int Mpad = ((N + 127) / 128) * 128;  // 20096

    char* p = (char*)d_ws;
    const size_t FP = (size_t)Mpad * 768 * sizeof(float);
    const size_t BF = (size_t)Mpad * 768 * sizeof(unsigned short);
    float* z = (float*)p;                 p += FP;
    unsigned short* Ahi = (unsigned short*)p;  p += BF;
    unsigned short* Alo = (unsigned short*)p;  p += BF;
    unsigned short* BThi = (unsigned short*)p; p += (size_t)768 * 768 * 2;
    unsigned short* BTlo = (unsigned short*)p; p += (size_t)768 * 768 * 2;
    float* ebuf = (float*)p;              p += (size_t)E * 12 * sizeof(float);
    float* el = (float*)p;                p += (size_t)N * 12 * sizeof(float);
    float* er = (float*)p;                p += (size_t)N * 12 * sizeof(float);
    unsigned* m = (unsigned*)p;           p += (size_t)N * 12 * sizeof(unsigned);
    float* denom = (float*)p;             p += (size_t)N * 12 * sizeof(float);
    int* counts = (int*)p;                p += (size_t)N * sizeof(int);
    int* cursor = (int*)p;                p += (size_t)N * sizeof(int);
    int* offsets = (int*)p;               p += (size_t)(N + 4) * sizeof(int);
    int* psrc = (int*)p;                  p += (size_t)E * sizeof(int);
    int* pdst = (int*)p;                  p += (size_t)E * sizeof(int);

    // ---- CSR (dst-sorted edges), static across layers ----
    csr_zero<<<(N + 255) / 256, 256, 0, stream>>>(counts, cursor, N);
    csr_count<<<(E + 255) / 256, 256, 0, stream>>>(dst, counts, E);
    csr_scan<<<1, 1024, 0, stream>>>(counts, offsets, N, E);
    csr_scatter<<<(E + 255) / 256, 256, 0, stream>>>(src, dst, offsets, cursor, psrc, pdst, E);

    // layer 0 input split
    decompose_a<<<(Mpad * 192 + 255) / 256, 256, 0, stream>>>(x0, Ahi, Alo, N, Mpad);

    // L0, L1: aggregate writes next layer's split into Ahi/Alo (mode 1)
    run_layer(W[0], al[0], ar[0], bs[0], offsets, psrc, pdst,
              Ahi, Alo, BThi, BTlo, z, nullptr, ebuf, el, er, m, denom,
              N, Mpad, E, 12, 64, true, 1, stream);
    run_layer(W[1], al[1], ar[1], bs[1], offsets, psrc, pdst,
              Ahi, Alo, BThi, BTlo, z, nullptr, ebuf, el, er, m, denom,
              N, Mpad, E, 12, 64, true, 1, stream);
    // L2: fp32 out -> d_out (mode 0)
    run_layer(W[2], al[2], ar[2], bs[2], offsets, psrc, pdst,
              Ahi, Alo, BThi, BTlo, z, (float*)d_out, ebuf, el, er, m, denom,
              N, Mpad, E, 1, 768, false, 0, stream);
}

// Round 11
// 626.394 us; speedup vs baseline: 1.1870x; 1.1310x over previous
//
#include <hip/hip_runtime.h>
#include <cstdint>
#include <cstddef>

#define DINL __device__ __forceinline__

typedef __attribute__((ext_vector_type(8))) short bf16x8;
typedef __attribute__((ext_vector_type(4))) float f32x4;

// ---- order-preserving float <-> uint encoding for atomic max ----
DINL unsigned f32_ord(float f) {
    unsigned u = __float_as_uint(f);
    return (u & 0x80000000u) ? ~u : (u | 0x80000000u);
}
DINL float ord_f32(unsigned v) {
    return (v & 0x80000000u) ? __uint_as_float(v & 0x7FFFFFFFu)
                             : __uint_as_float(~v);
}

// ---- bf16 split helpers (RNE) ----
DINL unsigned short f2bf(float f) {
    unsigned u = __float_as_uint(f);
    unsigned r = u + 0x7FFFu + ((u >> 16) & 1u);
    return (unsigned short)(r >> 16);
}
DINL float bf2f(unsigned short h) { return __uint_as_float((unsigned)h << 16); }

// ---- async global->LDS, 16B per lane (dest = wave-uniform base + lane*16) ----
#define GLOAD_LDS16(g, l)                                                     \
    __builtin_amdgcn_global_load_lds(                                         \
        (const __attribute__((address_space(1))) void*)(g),                   \
        (__attribute__((address_space(3))) void*)(l), 16, 0, 0)

// =====================================================================
// decompose_a: fp32 [Nrows x 768] -> bf16 hi (+lo if write_lo), zero pad
// =====================================================================
__global__ void decompose_a(const float* __restrict__ x,
                            unsigned short* __restrict__ hi,
                            unsigned short* __restrict__ lo,
                            int Nrows, int Mpad, int write_lo) {
    int i4 = blockIdx.x * blockDim.x + threadIdx.x;
    int total = Mpad * 192;
    if (i4 >= total) return;
    int row = i4 / 192;
    float4 v = (row < Nrows) ? ((const float4*)x)[i4]
                             : make_float4(0.f, 0.f, 0.f, 0.f);
    ushort4 h, l;
    h.x = f2bf(v.x); l.x = f2bf(v.x - bf2f(h.x));
    h.y = f2bf(v.y); l.y = f2bf(v.y - bf2f(h.y));
    h.z = f2bf(v.z); l.z = f2bf(v.z - bf2f(h.z));
    h.w = f2bf(v.w); l.w = f2bf(v.w - bf2f(h.w));
    ((ushort4*)hi)[i4] = h;
    if (write_lo) ((ushort4*)lo)[i4] = l;
}

// =====================================================================
// decompose_bT: W fp32 [768(K) x 768(N)] -> BhiT (+BloT) bf16 [N x K]
// =====================================================================
__global__ __launch_bounds__(256) void decompose_bT(const float* __restrict__ W,
                                                    unsigned short* __restrict__ hiT,
                                                    unsigned short* __restrict__ loT,
                                                    int write_lo) {
    __shared__ float tile[64][65];
    int k0 = blockIdx.x * 64, n0 = blockIdx.y * 64;
    int t = threadIdx.x;
#pragma unroll
    for (int i = 0; i < 16; ++i) {
        int idx = t + i * 256;
        int r = idx >> 6, c = idx & 63;
        tile[r][c] = W[(size_t)(k0 + r) * 768 + n0 + c];
    }
    __syncthreads();
#pragma unroll
    for (int i = 0; i < 16; ++i) {
        int idx = t + i * 256;
        int r = idx >> 6, c = idx & 63;
        float v = tile[c][r];
        unsigned short h = f2bf(v);
        hiT[(size_t)(n0 + r) * 768 + k0 + c] = h;
        if (write_lo) loT[(size_t)(n0 + r) * 768 + k0 + c] = f2bf(v - bf2f(h));
    }
}

// =====================================================================
// MFMA GEMM, templated precision:
//   FULL=1: C = Ahi*Bhi + Ahi*Blo + Alo*Bhi (near-fp32; 64KB LDS, 2 blk/CU)
//   FULL=0: C = Ahi*Bhi (1-pass bf16;        32KB LDS, 4 blk/CU = 32 waves)
// 128x128 tile, BK=32, 8 waves (4x2, 512 thr), 2-phase dbuf pipeline.
// Epilogue (do_attn): el/er per-head dot via 16-lane xor-reduce.
// =====================================================================
template<int FULL>
__global__ __launch_bounds__(512) void gemm_fused_bf16(
        const unsigned short* __restrict__ Ahi, const unsigned short* __restrict__ Alo,
        const unsigned short* __restrict__ BThi, const unsigned short* __restrict__ BTlo,
        float* __restrict__ C,
        const float* __restrict__ attl, const float* __restrict__ attr,
        float* __restrict__ el, float* __restrict__ er,
        int Nrows, int do_attn) {
    constexpr int K = 768, NC = 768, BKK = 32, NT = K / BKK;   // 24 K-steps
    __shared__ __align__(16) unsigned short AsH[2][128 * BKK];
    __shared__ __align__(16) unsigned short BsH[2][128 * BKK];
    __shared__ __align__(16) unsigned short AsL[FULL ? 2 : 1][FULL ? 128 * BKK : 8];
    __shared__ __align__(16) unsigned short BsL[FULL ? 2 : 1][FULL ? 128 * BKK : 8];
    const int t = threadIdx.x, w = t >> 6, l = t & 63;
    const int m0 = blockIdx.x * 128, n0 = blockIdx.y * 128;
    const int wr = w >> 1, wc = w & 1;          // 4x2 wave grid; wave owns 32x64

    f32x4 acc[2][4] = {};

    const int srow = w * 16 + (l >> 2);          // each wave stages 16 rows
    const int scol = (l & 3) * 8;
    const int kr = (l >> 4) * 8;

    auto stage = [&](int buf, int k0) {
        const size_t ga = (size_t)(m0 + srow) * K + k0 + scol;
        const size_t gb = (size_t)(n0 + srow) * K + k0 + scol;
        const int lofs = (w * 16) * BKK;
        GLOAD_LDS16(Ahi + ga, &AsH[buf][lofs]);
        GLOAD_LDS16(BThi + gb, &BsH[buf][lofs]);
        if constexpr (FULL) {
            GLOAD_LDS16(Alo + ga, &AsL[buf][lofs]);
            GLOAD_LDS16(BTlo + gb, &BsL[buf][lofs]);
        }
    };

    // prologue: fill buffer 0, full drain
    stage(0, 0);
    asm volatile("s_waitcnt vmcnt(0)" ::: "memory");
    __builtin_amdgcn_s_barrier();

    for (int tt = 0; tt < NT; ++tt) {
        const int cur = tt & 1;
        if (tt < NT - 1) stage(cur ^ 1, (tt + 1) * BKK);   // async prefetch

        bf16x8 fbh[4], fbl[4];
#pragma unroll
        for (int j = 0; j < 4; ++j) {
            const int row = (wc * 64 + j * 16 + (l & 15)) * BKK + kr;
            fbh[j] = *(const bf16x8*)&BsH[cur][row];
            if constexpr (FULL) fbl[j] = *(const bf16x8*)&BsL[cur][row];
        }
        __builtin_amdgcn_s_setprio(1);
#pragma unroll
        for (int i = 0; i < 2; ++i) {
            const int row = (wr * 32 + i * 16 + (l & 15)) * BKK + kr;
            bf16x8 fah = *(const bf16x8*)&AsH[cur][row];
#pragma unroll
            for (int j = 0; j < 4; ++j)
                acc[i][j] = __builtin_amdgcn_mfma_f32_16x16x32_bf16(fah, fbh[j], acc[i][j], 0, 0, 0);
            if constexpr (FULL) {
                bf16x8 fal = *(const bf16x8*)&AsL[cur][row];
#pragma unroll
                for (int j = 0; j < 4; ++j) {
                    acc[i][j] = __builtin_amdgcn_mfma_f32_16x16x32_bf16(fah, fbl[j], acc[i][j], 0, 0, 0);
                    acc[i][j] = __builtin_amdgcn_mfma_f32_16x16x32_bf16(fal, fbh[j], acc[i][j], 0, 0, 0);
                }
            }
        }
        __builtin_amdgcn_s_setprio(0);

        // prefetch landed + all waves done reading buf[cur]
        asm volatile("s_waitcnt vmcnt(0)" ::: "memory");
        __builtin_amdgcn_s_barrier();
    }

    // C/D layout: col=lane&15, row=(lane>>4)*4+reg  [m89-verified]
    const int crow = m0 + wr * 32 + (l >> 4) * 4;
    const int ccol = n0 + wc * 64 + (l & 15);
#pragma unroll
    for (int i = 0; i < 2; ++i)
#pragma unroll
        for (int j = 0; j < 4; ++j)
#pragma unroll
            for (int r = 0; r < 4; ++r)
                C[(size_t)(crow + i * 16 + r) * NC + ccol + j * 16] = acc[i][j][r];

    if (do_attn) {
        const int h = blockIdx.y * 2 + wc;
        float alc[4], arc[4];
#pragma unroll
        for (int j = 0; j < 4; ++j) {
            alc[j] = attl[h * 64 + (l & 15) + j * 16];
            arc[j] = attr[h * 64 + (l & 15) + j * 16];
        }
#pragma unroll
        for (int i = 0; i < 2; ++i)
#pragma unroll
            for (int r = 0; r < 4; ++r) {
                float sl = 0.f, sr = 0.f;
#pragma unroll
                for (int j = 0; j < 4; ++j) {
                    sl += acc[i][j][r] * alc[j];
                    sr += acc[i][j][r] * arc[j];
                }
#pragma unroll
                for (int o = 1; o < 16; o <<= 1) {
                    sl += __shfl_xor(sl, o);
                    sr += __shfl_xor(sr, o);
                }
                int row = crow + i * 16 + r;
                if ((l & 15) == 0 && row < Nrows) {
                    el[row * 12 + h] = sl;
                    er[row * 12 + h] = sr;
                }
            }
    }
}

// =====================================================================
// el/er standalone (layer 2 only: H=1 head spans all n-blocks)
// =====================================================================
__global__ __launch_bounds__(256) void el_er_kernel(const float* __restrict__ z,
                                                    const float* __restrict__ al,
                                                    const float* __restrict__ ar,
                                                    float* __restrict__ el,
                                                    float* __restrict__ er,
                                                    int N, int H, int Dh) {
    int wid = (blockIdx.x * 256 + threadIdx.x) >> 6;
    int lane = threadIdx.x & 63;
    if (wid >= N * H) return;
    int n = wid / H, h = wid % H;
    const float* zr = z + (size_t)n * (H * Dh) + h * Dh;
    const float* alr = al + h * Dh;
    const float* arr = ar + h * Dh;
    float sl = 0.f, sr = 0.f;
    for (int d = lane; d < Dh; d += 64) {
        float zv = zr[d];
        sl += zv * alr[d];
        sr += zv * arr[d];
    }
#pragma unroll
    for (int o = 32; o; o >>= 1) {
        sl += __shfl_down(sl, o);
        sr += __shfl_down(sr, o);
    }
    if (lane == 0) { el[wid] = sl; er[wid] = sr; }
}

__global__ void init_mdenom(unsigned* __restrict__ m, float* __restrict__ denom, int n) {
    int i = blockIdx.x * blockDim.x + threadIdx.x;
    if (i < n) { m[i] = 0u; denom[i] = 0.f; }
}

// =====================================================================
// edge kernels operate in CSR position order (psrc/pdst arrays)
// =====================================================================
__global__ void edge_e_kernel(const int* __restrict__ psrc, const int* __restrict__ pdst,
                              const float* __restrict__ el, const float* __restrict__ er,
                              float* __restrict__ e, unsigned* __restrict__ m,
                              int E, int H) {
    int i = blockIdx.x * blockDim.x + threadIdx.x;
    if (i >= E * H) return;
    int p = i / H, h = i - p * H;
    int s = psrc[p], d = pdst[p];
    float v = el[s * H + h] + er[d * H + h];
    v = (v >= 0.f) ? v : 0.2f * v;
    e[i] = v;
    atomicMax(&m[d * H + h], f32_ord(v));
}

__global__ void edge_ex_kernel(const int* __restrict__ pdst,
                               float* __restrict__ e, const unsigned* __restrict__ m,
                               float* __restrict__ denom, int E, int H) {
    int i = blockIdx.x * blockDim.x + threadIdx.x;
    if (i >= E * H) return;
    int p = i / H, h = i - p * H;
    int d = pdst[p];
    float x = expf(e[i] - ord_f32(m[d * H + h]));
    e[i] = x;
    atomicAdd(&denom[d * H + h], x);
}

// =====================================================================
// CSR build
// =====================================================================
__global__ void csr_zero(int* __restrict__ counts, int* __restrict__ cursor, int N) {
    int i = blockIdx.x * blockDim.x + threadIdx.x;
    if (i < N) { counts[i] = 0; cursor[i] = 0; }
}

__global__ void csr_count(const int* __restrict__ dst, int* __restrict__ counts, int E) {
    int i = blockIdx.x * blockDim.x + threadIdx.x;
    if (i < E) atomicAdd(&counts[dst[i]], 1);
}

__global__ __launch_bounds__(1024) void csr_scan(const int* __restrict__ counts,
                                                 int* __restrict__ offsets, int N, int E) {
    __shared__ int part[1024];
    const int t = threadIdx.x;
    const int CH = (N + 1023) / 1024;
    const int base = t * CH;
    int s = 0;
    for (int i = 0; i < CH; ++i) {
        int idx = base + i;
        if (idx < N) s += counts[idx];
    }
    part[t] = s;
    __syncthreads();
    for (int o = 1; o < 1024; o <<= 1) {
        int v = (t >= o) ? part[t - o] : 0;
        __syncthreads();
        part[t] += v;
        __syncthreads();
    }
    int run = (t > 0) ? part[t - 1] : 0;
    for (int i = 0; i < CH; ++i) {
        int idx = base + i;
        if (idx < N) { offsets[idx] = run; run += counts[idx]; }
    }
    if (t == 1023) offsets[N] = E;
}

__global__ void csr_scatter(const int* __restrict__ src, const int* __restrict__ dst,
                            const int* __restrict__ offsets, int* __restrict__ cursor,
                            int* __restrict__ psrc, int* __restrict__ pdst, int E) {
    int e = blockIdx.x * blockDim.x + threadIdx.x;
    if (e >= E) return;
    int d = dst[e];
    int pos = offsets[d] + atomicAdd(&cursor[d], 1);
    psrc[pos] = src[e];
    pdst[pos] = d;
}

// =====================================================================
// CSR aggregation, fused residual+bias+ELU.
// THREE waves per dst node (one per 256-col segment q), 2-way unrolled
// edge loop.
// mode==0: write fp32 out (final layer -> d_out), covers N.
// mode==1: write bf16 hi+lo split (next layer 3-pass GEMM), covers Mpad.
// mode==2: write bf16 hi only   (next layer 1-pass GEMM), covers Mpad.
// =====================================================================
__global__ __launch_bounds__(256) void aggregate_csr(const int* __restrict__ offsets,
                                                     const int* __restrict__ psrc,
                                                     const float* __restrict__ z,
                                                     const float* __restrict__ ex,
                                                     const float* __restrict__ denom,
                                                     const float* __restrict__ bias,
                                                     float* __restrict__ out,
                                                     unsigned short* __restrict__ nAhi,
                                                     unsigned short* __restrict__ nAlo,
                                                     int N, int Mpad, int H, int Dh,
                                                     int use_elu, int mode) {
    int wid = (blockIdx.x * 256 + threadIdx.x) >> 6;
    int lane = threadIdx.x & 63;
    int limit = mode ? Mpad : N;
    int d = wid / 3, q = wid - d * 3;
    if (d >= limit) return;
    const int idx = lane + 64 * q;                 // float4 index in the 768-row

    if (d >= N) {                                  // pad rows: zero split only
        ushort4 zz = {0, 0, 0, 0};
        ((ushort4*)nAhi)[(size_t)d * 192 + idx] = zz;
        if (mode == 1) ((ushort4*)nAlo)[(size_t)d * 192 + idx] = zz;
        return;
    }

    float inv_den = 0.f;
    if (lane < H) inv_den = 1.0f / denom[d * H + lane];
    const int h = (4 * idx) / Dh;                  // head of this float4

    float4 a = ((const float4*)(z + (size_t)d * 768))[idx];
    float4 b = ((const float4*)bias)[idx];
    float4 acc = make_float4(a.x + b.x, a.y + b.y, a.z + b.z, a.w + b.w);

    const int beg = offsets[d], end = offsets[d + 1];
    int p = beg;
    for (; p + 1 < end; p += 2) {
        int s0 = psrc[p], s1 = psrc[p + 1];
        float al0 = 0.f, al1 = 0.f;
        if (lane < H) {
            al0 = ex[(size_t)p * H + lane] * inv_den;
            al1 = ex[(size_t)(p + 1) * H + lane] * inv_den;
        }
        float4 z0 = ((const float4*)(z + (size_t)s0 * 768))[idx];
        float4 z1 = ((const float4*)(z + (size_t)s1 * 768))[idx];
        float aa0 = __shfl(al0, h), aa1 = __shfl(al1, h);
        acc.x += aa0 * z0.x + aa1 * z1.x;
        acc.y += aa0 * z0.y + aa1 * z1.y;
        acc.z += aa0 * z0.z + aa1 * z1.z;
        acc.w += aa0 * z0.w + aa1 * z1.w;
    }
    if (p < end) {
        int s0 = psrc[p];
        float al0 = 0.f;
        if (lane < H) al0 = ex[(size_t)p * H + lane] * inv_den;
        float4 z0 = ((const float4*)(z + (size_t)s0 * 768))[idx];
        float aa0 = __shfl(al0, h);
        acc.x += aa0 * z0.x;
        acc.y += aa0 * z0.y;
        acc.z += aa0 * z0.z;
        acc.w += aa0 * z0.w;
    }

    float4 v = acc;
    if (use_elu) {
        v.x = v.x > 0.f ? v.x : expm1f(v.x);
        v.y = v.y > 0.f ? v.y : expm1f(v.y);
        v.z = v.z > 0.f ? v.z : expm1f(v.z);
        v.w = v.w > 0.f ? v.w : expm1f(v.w);
    }
    if (mode) {
        ushort4 h4;
        h4.x = f2bf(v.x); h4.y = f2bf(v.y);
        h4.z = f2bf(v.z); h4.w = f2bf(v.w);
        ((ushort4*)nAhi)[(size_t)d * 192 + idx] = h4;
        if (mode == 1) {
            ushort4 l4;
            l4.x = f2bf(v.x - bf2f(h4.x));
            l4.y = f2bf(v.y - bf2f(h4.y));
            l4.z = f2bf(v.z - bf2f(h4.z));
            l4.w = f2bf(v.w - bf2f(h4.w));
            ((ushort4*)nAlo)[(size_t)d * 192 + idx] = l4;
        }
    } else {
        ((float4*)(out + (size_t)d * 768))[idx] = v;
    }
}

// =====================================================================
// host-side layer driver
// =====================================================================
static void run_layer(const float* W, const float* al, const float* ar,
                      const float* bias,
                      const int* offsets, const int* psrc, const int* pdst,
                      unsigned short* Ahi, unsigned short* Alo,
                      unsigned short* BThi, unsigned short* BTlo,
                      float* z, float* out, float* ebuf, float* el, float* er,
                      unsigned* m, float* denom,
                      int N, int Mpad, int E, int H, int Dh, bool use_elu,
                      int agg_mode, int full_prec, hipStream_t stream) {
    decompose_bT<<<dim3(12, 12), 256, 0, stream>>>(W, BThi, BTlo, full_prec);
    if (full_prec)
        gemm_fused_bf16<1><<<dim3(Mpad / 128, 6), 512, 0, stream>>>(
            Ahi, Alo, BThi, BTlo, z, al, ar, el, er, N, H == 12 ? 1 : 0);
    else
        gemm_fused_bf16<0><<<dim3(Mpad / 128, 6), 512, 0, stream>>>(
            Ahi, Alo, BThi, BTlo, z, al, ar, el, er, N, H == 12 ? 1 : 0);
    if (H != 12)
        el_er_kernel<<<(N * H * 64 + 255) / 256, 256, 0, stream>>>(z, al, ar, el, er, N, H, Dh);
    init_mdenom<<<(N * H + 255) / 256, 256, 0, stream>>>(m, denom, N * H);
    edge_e_kernel<<<(E * H + 255) / 256, 256, 0, stream>>>(psrc, pdst, el, er, ebuf, m, E, H);
    edge_ex_kernel<<<(E * H + 255) / 256, 256, 0, stream>>>(pdst, ebuf, m, denom, E, H);
    int limit = agg_mode ? Mpad : N;
    aggregate_csr<<<((size_t)limit * 3 * 64 + 255) / 256, 256, 0, stream>>>(
        offsets, psrc, z, ebuf, denom, bias, out, Ahi, Alo,
        N, Mpad, H, Dh, use_elu ? 1 : 0, agg_mode);
}

extern "C" void kernel_launch(void* const* d_in, const int* in_sizes, int n_in,
                              void* d_out, int out_size, void* d_ws, size_t ws_size,
                              hipStream_t stream) {
    const float* x0 = (const float*)d_in[0];
    const int* src = (const int*)d_in[1];
    const int* dst = (const int*)d_in[2];
    const float* W[3]  = {(const float*)d_in[3], (const float*)d_in[7],  (const float*)d_in[11]};
    const float* al[3] = {(const float*)d_in[4], (const float*)d_in[8],  (const float*)d_in[12]};
    const float* ar[3] = {(const float*)d_in[5], (const float*)d_in[9],  (const float*)d_in[13]};
    const float* bs[3] = {(const float*)d_in[6], (const float*)d_in[10], (const float*)d_in[14]};

    const int N = in_sizes[0] / 768;           // 20000
    const int E = in_sizes[1];                 // 100000
    const int Mpad = ((N + 127) / 128) * 128;  // 20096

    char* p = (char*)d_ws;
    const size_t FP = (size_t)Mpad * 768 * sizeof(float);
    const size_t BF = (size_t)Mpad * 768 * sizeof(unsigned short);
    float* z = (float*)p;                 p += FP;
    unsigned short* Ahi = (unsigned short*)p;  p += BF;
    unsigned short* Alo = (unsigned short*)p;  p += BF;
    unsigned short* BThi = (unsigned short*)p; p += (size_t)768 * 768 * 2;
    unsigned short* BTlo = (unsigned short*)p; p += (size_t)768 * 768 * 2;
    float* ebuf = (float*)p;              p += (size_t)E * 12 * sizeof(float);
    float* el = (float*)p;                p += (size_t)N * 12 * sizeof(float);
    float* er = (float*)p;                p += (size_t)N * 12 * sizeof(float);
    unsigned* m = (unsigned*)p;           p += (size_t)N * 12 * sizeof(unsigned);
    float* denom = (float*)p;             p += (size_t)N * 12 * sizeof(float);
    int* counts = (int*)p;                p += (size_t)N * sizeof(int);
    int* cursor = (int*)p;                p += (size_t)N * sizeof(int);
    int* offsets = (int*)p;               p += (size_t)(N + 4) * sizeof(int);
    int* psrc = (int*)p;                  p += (size_t)E * sizeof(int);
    int* pdst = (int*)p;                  p += (size_t)E * sizeof(int);

    // ---- CSR (dst-sorted edges), static across layers ----
    csr_zero<<<(N + 255) / 256, 256, 0, stream>>>(counts, cursor, N);
    csr_count<<<(E + 255) / 256, 256, 0, stream>>>(dst, counts, E);
    csr_scan<<<1, 1024, 0, stream>>>(counts, offsets, N, E);
    csr_scatter<<<(E + 255) / 256, 256, 0, stream>>>(src, dst, offsets, cursor, psrc, pdst, E);

    // layer 0 input split: hi only (L0 GEMM is 1-pass)
    decompose_a<<<(Mpad * 192 + 255) / 256, 256, 0, stream>>>(x0, Ahi, Alo, N, Mpad, 0);

    // L0: 1-pass GEMM; aggregate writes hi-only next input (L1 is 1-pass)
    run_layer(W[0], al[0], ar[0], bs[0], offsets, psrc, pdst,
              Ahi, Alo, BThi, BTlo, z, nullptr, ebuf, el, er, m, denom,
              N, Mpad, E, 12, 64, true, /*agg_mode=*/2, /*full=*/0, stream);
    // L1: 1-pass GEMM; aggregate writes hi+lo next input (L2 is 3-pass)
    run_layer(W[1], al[1], ar[1], bs[1], offsets, psrc, pdst,
              Ahi, Alo, BThi, BTlo, z, nullptr, ebuf, el, er, m, denom,
              N, Mpad, E, 12, 64, true, /*agg_mode=*/1, /*full=*/0, stream);
    // L2: 3-pass GEMM (near-fp32); fp32 out -> d_out
    run_layer(W[2], al[2], ar[2], bs[2], offsets, psrc, pdst,
              Ahi, Alo, BThi, BTlo, z, (float*)d_out, ebuf, el, er, m, denom,
              N, Mpad, E, 1, 768, false, /*agg_mode=*/0, /*full=*/1, stream);
}